// Round 6
// baseline (201.032 us; speedup 1.0000x reference)
//
#include <hip/hip_runtime.h>
#include <math.h>

#define B 16
#define D 8
#define FDIM 2
#define N 512
#define E 10            // D + FDIM
#define NP36 36         // pairs a<=d
#define GJW (2*E)       // augmented width for Gauss-Jordan
#define NT 4            // i-tiles per (pair,b)
#define TIL 128         // i-tile size
#define NQ (NP36*B*NT)        // 2304 k_q blocks
#define NPREP (NP36*B + B*D)  // 576 pair + 128 A blocks
#define LOG2E 1.44269504088896340736f

// ---- workspace layout (float offsets) ----
#define OFF_MUD  0           // B*D            = 128
#define OFF_V    128         // B*D*E          = 1280
#define OFF_EDDP 1408        // NP36*B*NT      = 2304
#define OFF_TRP  3712        // D*B*NT         = 512
#define OFF_XNU  4224        // B*N*12         = 98304   [x0..x9,1,0]
#define OFF_FB   102528      // NP36*B*N       = 294912  beta_d*2^cb
#define OFF_CB   397440      // NP36*B*N       = 294912  cb (log2 domain)
#define OFF_T    692352      // NP36*B*N*12    = 3538944 [t0..t9, ba*2^ca, 2^ca]
// total 4231296 floats = 16.9 MB

__device__ __forceinline__ void decode_pair(int p36, int* pa, int* pd) {
  int a = 0, rem = p36;
  while (rem >= D - a) { rem -= (D - a); a++; }
  *pa = a; *pd = a + rem;
}

__device__ __forceinline__ float wave_reduce(float v) {
#pragma unroll
  for (int off = 32; off > 0; off >>= 1) v += __shfl_down(v, off);
  return v;
}

__device__ __forceinline__ float fast_exp2(float x) {
#if __has_builtin(__builtin_amdgcn_exp2f)
  return __builtin_amdgcn_exp2f(x);
#else
  return exp2f(x);
#endif
}

// Single-wave Gauss-Jordan with partial pivoting on augmented E x GJW system
// in LDS. Call from ALL threads; only wave 0 acts. No block barriers inside —
// caller must __syncthreads() after. Lane-uniform return (wave 0 only):
// log|det(left)| . Wave-lockstep LDS ordering makes it race-free.
__device__ __forceinline__ float gj_wave(float (*M)[GJW], float* colfac,
                                         int tid) {
  float detprod = 1.0f;
  if (tid < 64) {
    int lane = tid;
    for (int k = 0; k < E; k++) {
      // wave-parallel pivot search over rows k..E-1 (lanes 0..15 butterfly)
      float v = (lane < E && lane >= k) ? fabsf(M[lane][k]) : -1.0f;
      int idx = lane;
#pragma unroll
      for (int off = 8; off > 0; off >>= 1) {
        float ov = __shfl_xor(v, off);
        int oi = __shfl_xor(idx, off);
        if (ov > v) { v = ov; idx = oi; }
      }
      int pr = __shfl(idx, 0);
      float piv = M[pr][k];            // broadcast read
      detprod *= fabsf(piv);
      if (lane < GJW) {                // swap + normalize (lockstep: loads first)
        float rowp = M[pr][lane];
        float rowk = M[k][lane];
        M[pr][lane] = rowk;
        M[k][lane] = rowp / piv;
      }
      if (lane < E) colfac[lane] = M[lane][k];   // post-swap column factors
      for (int i2 = lane; i2 < E * GJW; i2 += 64) {
        int r = i2 / GJW, c = i2 % GJW;
        if (r != k) M[r][c] -= colfac[r] * M[k][c];
      }
    }
  }
  return logf(detprod);
}

// ---------------------------------------------------------------------------
// k_prep: blocks [0, NP36*B): per-(pair,b) -> T rows, FB, CB.
//         blocks [NP36*B, +B*D): mu_delta[b,d], V[b,d,:] (+XNU when d==0).
__global__ __launch_bounds__(256) void k_prep(
    const float* __restrict__ obs_mean, const float* __restrict__ obs_var,
    const float* __restrict__ action_mean, const float* __restrict__ action_var,
    const float* __restrict__ cross_cov, const float* __restrict__ X,
    const float* __restrict__ ell, const float* __restrict__ alpha_sq,
    const float* __restrict__ beta, float* __restrict__ ws) {
  __shared__ float M[E][GJW];
  __shared__ float colfac[E];
  __shared__ float s_logdet, s_ldl;
  __shared__ float sMu[E], sSig[E * E], siLa[E], siLd[E];
  __shared__ float wred[4][11];
  __shared__ float wsh[E];

  int tid = threadIdx.x;
  int bx = blockIdx.x;

  if (bx >= NP36 * B) {
    // ===== A-path =====
    int bd = bx - NP36 * B;
    int b = bd / D, d = bd % D;
    if (tid < E) {
      sMu[tid] = (tid < D) ? obs_mean[b * D + tid] : action_mean[b * FDIM + tid - D];
    }
    for (int idx = tid; idx < E * E; idx += 256) {
      int e = idx / E, f = idx % E;
      float v;
      if (e < D && f < D)      v = obs_var[(b * D + e) * D + f];
      else if (e < D)          v = cross_cov[(b * D + e) * FDIM + (f - D)];
      else if (f < D)          v = cross_cov[(b * D + f) * FDIM + (e - D)];
      else                     v = action_var[(b * FDIM + (e - D)) * FDIM + (f - D)];
      sSig[idx] = v;
    }
    __syncthreads();
    for (int idx = tid; idx < E * GJW; idx += 256) {
      int r = idx / GJW, c = idx % GJW;
      float v;
      if (c < E) {
        v = sSig[r * E + c];
        if (r == c) { float l = ell[d * E + r]; v += l * l; }
      } else {
        v = (c - E == r) ? 1.0f : 0.0f;
      }
      M[r][c] = v;
    }
    if (tid == 64) {           // wave 1: logdetLam while wave 0 does GJ
      float s = 0.0f;
#pragma unroll
      for (int e = 0; e < E; e++) { float l = ell[d * E + e]; s += logf(l * l); }
      s_ldl = s;
    }
    __syncthreads();
    float ld = gj_wave(M, colfac, tid);   // M[r][E+c] = Ainv
    if (tid == 0) s_logdet = ld;
    __syncthreads();
    float c0 = 0.5f * (s_ldl - s_logdet);
    float a2 = alpha_sq[d];
    float acc_mu = 0.0f, acc_w[E];
#pragma unroll
    for (int e = 0; e < E; e++) acc_w[e] = 0.0f;
    bool wx = (d == 0);
    for (int n = tid; n < N; n += 256) {
      float x[E];
#pragma unroll
      for (int e = 0; e < E; e++) x[e] = X[n * E + e] - sMu[e];
      if (wx) {
        float* xr = ws + OFF_XNU + ((size_t)b * N + n) * 12;
#pragma unroll
        for (int e = 0; e < E; e++) xr[e] = x[e];
        xr[10] = 1.0f; xr[11] = 0.0f;
      }
      float quad = 0.0f;
#pragma unroll
      for (int e = 0; e < E; e++) {
        float te = 0.0f;
#pragma unroll
        for (int f = 0; f < E; f++) te += M[e][E + f] * x[f];
        quad += x[e] * te;
      }
      float qval = a2 * __expf(c0 - 0.5f * quad);
      float bq = beta[d * N + n] * qval;
      acc_mu += bq;
#pragma unroll
      for (int e = 0; e < E; e++) acc_w[e] += bq * x[e];
    }
    int wid = tid >> 6, lane = tid & 63;
    float r = wave_reduce(acc_mu);
    if (lane == 0) wred[wid][0] = r;
#pragma unroll
    for (int e = 0; e < E; e++) {
      r = wave_reduce(acc_w[e]);
      if (lane == 0) wred[wid][e + 1] = r;
    }
    __syncthreads();
    if (tid < 11) {
      float s = wred[0][tid] + wred[1][tid] + wred[2][tid] + wred[3][tid];
      if (tid == 0) ws[OFF_MUD + b * D + d] = s;
      else wsh[tid - 1] = s;
    }
    __syncthreads();
    if (tid == 0) {
      float u[E];
#pragma unroll
      for (int f = 0; f < E; f++) {
        float s = 0.0f;
#pragma unroll
        for (int g = 0; g < E; g++) s += M[f][E + g] * wsh[g];
        u[f] = s;
      }
#pragma unroll
      for (int e = 0; e < E; e++) {
        float s = 0.0f;
#pragma unroll
        for (int f = 0; f < E; f++) s += sSig[e * E + f] * u[f];
        ws[OFF_V + (b * D + d) * E + e] = s;
      }
    }
    return;
  }

  // ===== pair path: T, FB, CB for (p36, b) =====
  int p36 = bx / B, b = bx % B;
  int a, d;
  decode_pair(p36, &a, &d);
  int pb = p36 * B + b;
  if (tid < E) {
    sMu[tid] = (tid < D) ? obs_mean[b * D + tid] : action_mean[b * FDIM + tid - D];
    float la = ell[a * E + tid]; siLa[tid] = 1.0f / (la * la);
    float ld = ell[d * E + tid]; siLd[tid] = 1.0f / (ld * ld);
  }
  for (int idx = tid; idx < E * E; idx += 256) {
    int e = idx / E, f = idx % E;
    float v;
    if (e < D && f < D)      v = obs_var[(b * D + e) * D + f];
    else if (e < D)          v = cross_cov[(b * D + e) * FDIM + (f - D)];
    else if (f < D)          v = cross_cov[(b * D + f) * FDIM + (e - D)];
    else                     v = action_var[(b * FDIM + (e - D)) * FDIM + (f - D)];
    sSig[idx] = v;
  }
  __syncthreads();
  for (int idx = tid; idx < E * GJW; idx += 256) {
    int r = idx / GJW, c = idx % GJW;
    float v;
    if (c < E) v = sSig[r * E + c] * (siLa[c] + siLd[c]) + ((r == c) ? 1.0f : 0.0f);
    else       v = sSig[r * E + (c - E)];
    M[r][c] = v;
  }
  __syncthreads();
  float ld = gj_wave(M, colfac, tid);    // M[r][E+c] = S (symmetric), ld = logdetR
  if (tid == 0) s_logdet = ld;
  __syncthreads();
  float ldr = s_logdet;
  float lga = logf(alpha_sq[a]);
  float lgd = logf(alpha_sq[d]);
  for (int n = tid; n < N; n += 256) {
    float x[E], pa[E], pd[E];
    float s2a = 0.0f, s2b = 0.0f;
#pragma unroll
    for (int e = 0; e < E; e++) {
      float xe = X[n * E + e] - sMu[e];
      x[e] = xe;
      pa[e] = xe * siLa[e];
      pd[e] = xe * siLd[e];
      s2a += xe * pa[e];
      s2b += xe * pd[e];
    }
    float spa[E], spd[E];
#pragma unroll
    for (int e = 0; e < E; e++) {
      float ta = 0.0f, td = 0.0f;
#pragma unroll
      for (int f = 0; f < E; f++) {
        float s = M[e][E + f];
        ta += s * pa[f];
        td += s * pd[f];
      }
      spa[e] = ta; spd[e] = td;
    }
    float da = 0.0f, db = 0.0f;
#pragma unroll
    for (int e = 0; e < E; e++) { da += pa[e] * spa[e]; db += pd[e] * spd[e]; }
    float ca = LOG2E * (lga - 0.5f * s2a + 0.5f * da - 0.5f * ldr);
    float cb = LOG2E * (lgd - 0.5f * s2b + 0.5f * db);
    float Ei = fast_exp2(ca);
    float* Trow = ws + OFF_T + ((size_t)pb * N + n) * 12;
#pragma unroll
    for (int f = 0; f < E; f++) Trow[f] = LOG2E * siLd[f] * spa[f];
    Trow[10] = beta[a * N + n] * Ei;
    Trow[11] = Ei;
    ws[OFF_FB + (size_t)pb * N + n] = beta[d * N + n] * fast_exp2(cb);
    ws[OFF_CB + (size_t)pb * N + n] = cb;
  }
}

// ---------------------------------------------------------------------------
// k_q: per (pair, b, i-tile). wave = i-quarter (32 rows), lane = 8-j group.
// Per cell: 10-FMA dot + exp2 + 1 FMA into per-j accumulator.
__global__ __launch_bounds__(256, 3) void k_q(const float* __restrict__ invK,
                                              float* __restrict__ ws) {
  __shared__ float sT[TIL * 12];      // 6144 B: [t0..t9, baE, Ei] per row
  __shared__ float redw[8];

  int tid = threadIdx.x;
  int bx = blockIdx.x;
  int tile = bx & (NT - 1);
  int rest = bx >> 2;
  int b = rest & (B - 1);
  int p36 = rest >> 4;
  int a, d;
  decode_pair(p36, &a, &d);
  int pb = p36 * B + b;
  bool diag = (a == d);
  int i0 = tile * TIL;

  // stage T tile (pure float4 copy)
  {
    const float4* gT = (const float4*)(ws + OFF_T + ((size_t)pb * N + i0) * 12);
    float4* sT4 = (float4*)sT;
    for (int idx = tid; idx < TIL * 3; idx += 256) sT4[idx] = gT[idx];
  }
  // per-thread j fragment: 8 consecutive j
  int jgrp = tid & 63;
  int iq = tid >> 6;
  int j0 = jgrp * 8;
  float xj[8][10];
  {
    const float4* xp = (const float4*)(ws + OFF_XNU + ((size_t)b * N + j0) * 12);
#pragma unroll
    for (int r = 0; r < 8; r++) {
      float4 a0 = xp[r * 3], a1 = xp[r * 3 + 1], a2 = xp[r * 3 + 2];
      xj[r][0] = a0.x; xj[r][1] = a0.y; xj[r][2] = a0.z; xj[r][3] = a0.w;
      xj[r][4] = a1.x; xj[r][5] = a1.y; xj[r][6] = a1.z; xj[r][7] = a1.w;
      xj[r][8] = a2.x; xj[r][9] = a2.y;
    }
  }
  float acc[8], acctr[8];
#pragma unroll
  for (int k = 0; k < 8; k++) { acc[k] = 0.0f; acctr[k] = 0.0f; }
  __syncthreads();

  const float* invKa = invK + (size_t)a * N * N;
  int rbase = iq * 32;
#pragma unroll 2
  for (int il = 0; il < 32; il++) {
    int row = rbase + il;
    const float4* tp = (const float4*)&sT[row * 12];
    float4 t0 = tp[0], t1 = tp[1], t2 = tp[2];
    float baE = t2.z, Ei = t2.w;
    float kr[8];
    if (diag) {
      const float4* kp = (const float4*)(invKa + (size_t)(i0 + row) * N + j0);
      float4 r0 = kp[0], r1 = kp[1];
      kr[0] = r0.x; kr[1] = r0.y; kr[2] = r0.z; kr[3] = r0.w;
      kr[4] = r1.x; kr[5] = r1.y; kr[6] = r1.z; kr[7] = r1.w;
    }
#pragma unroll
    for (int k = 0; k < 8; k++) {
      float m = t0.x * xj[k][0];
      m = fmaf(t0.y, xj[k][1], m);
      m = fmaf(t0.z, xj[k][2], m);
      m = fmaf(t0.w, xj[k][3], m);
      m = fmaf(t1.x, xj[k][4], m);
      m = fmaf(t1.y, xj[k][5], m);
      m = fmaf(t1.z, xj[k][6], m);
      m = fmaf(t1.w, xj[k][7], m);
      m = fmaf(t2.x, xj[k][8], m);
      m = fmaf(t2.y, xj[k][9], m);
      float q = fast_exp2(m);
      acc[k] = fmaf(baE, q, acc[k]);
      if (diag) acctr[k] = fmaf(kr[k], Ei * q, acctr[k]);
    }
  }

  // epilogue: fold FB (and exp2(CB) for trace), then block-reduce
  float local = 0.0f;
  {
    const float4* fp = (const float4*)(ws + OFF_FB + (size_t)pb * N + j0);
    float4 f0 = fp[0], f1 = fp[1];
    local = f0.x * acc[0] + f0.y * acc[1] + f0.z * acc[2] + f0.w * acc[3] +
            f1.x * acc[4] + f1.y * acc[5] + f1.z * acc[6] + f1.w * acc[7];
  }
  float local_tr = 0.0f;
  if (diag) {
    const float4* cp = (const float4*)(ws + OFF_CB + (size_t)pb * N + j0);
    float4 c0 = cp[0], c1 = cp[1];
    local_tr = fast_exp2(c0.x) * acctr[0] + fast_exp2(c0.y) * acctr[1] +
               fast_exp2(c0.z) * acctr[2] + fast_exp2(c0.w) * acctr[3] +
               fast_exp2(c1.x) * acctr[4] + fast_exp2(c1.y) * acctr[5] +
               fast_exp2(c1.z) * acctr[6] + fast_exp2(c1.w) * acctr[7];
  }
  {
    float rr = wave_reduce(local);
    int wid = tid >> 6, lane = tid & 63;
    if (lane == 0) redw[wid] = rr;
    if (diag) {
      float rt = wave_reduce(local_tr);
      if (lane == 0) redw[4 + wid] = rt;
    }
    __syncthreads();
    if (tid == 0) {
      ws[OFF_EDDP + (p36 * B + b) * NT + tile] = redw[0] + redw[1] + redw[2] + redw[3];
      if (diag)
        ws[OFF_TRP + (a * B + b) * NT + tile] = redw[4] + redw[5] + redw[6] + redw[7];
    }
  }
}

// ---------------------------------------------------------------------------
// k_final: assembly (sums tile partials)
__global__ __launch_bounds__(64) void k_final(
    const float* __restrict__ obs_mean, const float* __restrict__ obs_var,
    const float* __restrict__ alpha_sq, const float* __restrict__ sigma_sq_eps,
    const float* __restrict__ ws, float* __restrict__ out) {
  int b = blockIdx.x;
  int tid = threadIdx.x;
  const float* mud = ws + OFF_MUD + b * D;
  if (tid < D) out[b * D + tid] = obs_mean[b * D + tid] + mud[tid];
  if (tid < D * D) {
    int i = tid / D, j = tid % D;
    int a = i < j ? i : j;
    int dd = i < j ? j : i;
    int p36 = a * D - a * (a - 1) / 2 + (dd - a);
    float edd = 0.0f;
#pragma unroll
    for (int tt = 0; tt < NT; tt++) edd += ws[OFF_EDDP + (p36 * B + b) * NT + tt];
    float sd = edd - mud[i] * mud[j];
    if (i == j) {
      float tr = 0.0f;
#pragma unroll
      for (int tt = 0; tt < NT; tt++) tr += ws[OFF_TRP + (i * B + b) * NT + tt];
      sd += alpha_sq[i] - tr + sigma_sq_eps[i];
    }
    const float* V = ws + OFF_V;
    float cxd = V[(b * D + j) * E + i];   // C_xd[b,i,j] = V[b,j,i]
    float cdx = V[(b * D + i) * E + j];   // C_xd[b,j,i] = V[b,i,j]
    out[B * D + b * D * D + tid] = obs_var[b * D * D + tid] + sd + cxd + cdx;
  }
}

// ---------------------------------------------------------------------------
extern "C" void kernel_launch(void* const* d_in, const int* in_sizes, int n_in,
                              void* d_out, int out_size, void* d_ws, size_t ws_size,
                              hipStream_t stream) {
  const float* obs_mean     = (const float*)d_in[0];
  const float* obs_var      = (const float*)d_in[1];
  const float* action_mean  = (const float*)d_in[2];
  const float* action_var   = (const float*)d_in[3];
  const float* cross_cov    = (const float*)d_in[4];
  const float* X_train      = (const float*)d_in[5];
  const float* ell          = (const float*)d_in[6];
  const float* alpha_sq     = (const float*)d_in[7];
  const float* sigma_sq_eps = (const float*)d_in[8];
  const float* beta         = (const float*)d_in[9];
  const float* inv_K        = (const float*)d_in[10];
  float* out = (float*)d_out;
  float* ws = (float*)d_ws;

  k_prep<<<NPREP, 256, 0, stream>>>(obs_mean, obs_var, action_mean, action_var,
                                    cross_cov, X_train, ell, alpha_sq, beta, ws);
  k_q<<<NQ, 256, 0, stream>>>(inv_K, ws);
  k_final<<<B, 64, 0, stream>>>(obs_mean, obs_var, alpha_sq, sigma_sq_eps, ws, out);
}